// Round 7
// baseline (312.256 us; speedup 1.0000x reference)
//
#include <hip/hip_runtime.h>

typedef short short8  __attribute__((ext_vector_type(8)));
typedef short short4v __attribute__((ext_vector_type(4)));
typedef float f32x4   __attribute__((ext_vector_type(4)));

#define NB 4
#define NS 4096
#define NE 1024
#define ND 64

__device__ __forceinline__ short f2bf(float f) {
    unsigned u = __builtin_bit_cast(unsigned, f);
    u = (u + 0x7FFFu + ((u >> 16) & 1u)) >> 16;
    return (short)u;
}
__device__ __forceinline__ float bf2f(short s) {
    unsigned u = ((unsigned)(unsigned short)s) << 16;
    return __builtin_bit_cast(float, u);
}

// ---- kernel 1: W transpose + concat + bf16 hi/lo split (scale folded into W_Q) ----
__global__ void prep_wt(const float* __restrict__ WQ, const float* __restrict__ WK,
                        const float* __restrict__ WV,
                        short* __restrict__ wthi, short* __restrict__ wtlo) {
    int idx = blockIdx.x * 256 + threadIdx.x;     // 192*1024
    if (idx >= 192 * NE) return;
    int n = idx >> 10, k = idx & (NE - 1);
    int sel = n >> 6, d = n & 63;
    const float* W = (sel == 0) ? WQ : (sel == 1 ? WK : WV);
    float v = W[k * ND + d];
    if (sel == 0) v *= 0.125f;                    // 1/sqrt(64), exact power of 2
    short hi = f2bf(v);
    short lo = f2bf(v - bf2f(hi));
    wthi[idx] = hi;
    wtlo[idx] = lo;
}

// ---- kernel 2: QKV projection (LDS-staged, KNOWN GOOD round-4 version) ----
__global__ __launch_bounds__(256) void proj_rope(
        const float* __restrict__ x,
        const short* __restrict__ wthi, const short* __restrict__ wtlo,
        short* __restrict__ qhi, short* __restrict__ qlo,
        short* __restrict__ khi, short* __restrict__ klo,
        short* __restrict__ vt) {
    __shared__ short Ahi[64][40], Alo[64][40];
    __shared__ short Bhi[192][40], Blo[192][40];
    const int tid = threadIdx.x;
    const int lane = tid & 63, wid = tid >> 6;
    const int wr = wid >> 1, wc = wid & 1;
    const int g = lane >> 4, cl = lane & 15;
    const int rb = blockIdx.x * 64;

    f32x4 zero4 = {0.f, 0.f, 0.f, 0.f};
    f32x4 acc[2][6];
    #pragma unroll
    for (int i = 0; i < 2; ++i)
        #pragma unroll
        for (int j = 0; j < 6; ++j) acc[i][j] = zero4;

    const int arow = tid >> 3, acol = (tid & 7) << 2;   // A stage: 32 rows x 32 cols per i
    const int bn = tid >> 2, bk = (tid & 3) << 3;       // B stage: 64 rows x 32 cols per i

    for (int k0 = 0; k0 < NE; k0 += 32) {
        #pragma unroll
        for (int i = 0; i < 2; ++i) {
            int r = arow + (i << 5);
            const float4 v = *(const float4*)(x + (rb + r) * NE + k0 + acol);
            float vv[4] = {v.x, v.y, v.z, v.w};
            short4v hv, lv;
            #pragma unroll
            for (int q = 0; q < 4; ++q) {
                short h = f2bf(vv[q]);
                hv[q] = h;
                lv[q] = f2bf(vv[q] - bf2f(h));
            }
            *(short4v*)&Ahi[r][acol] = hv;
            *(short4v*)&Alo[r][acol] = lv;
        }
        #pragma unroll
        for (int i = 0; i < 3; ++i) {
            int n = bn + (i << 6);
            *(short8*)&Bhi[n][bk] = *(const short8*)(wthi + n * NE + k0 + bk);
            *(short8*)&Blo[n][bk] = *(const short8*)(wtlo + n * NE + k0 + bk);
        }
        __syncthreads();
        short8 ah[2], al[2];
        #pragma unroll
        for (int rt = 0; rt < 2; ++rt) {
            ah[rt] = *(short8*)&Ahi[(wr << 5) + (rt << 4) + cl][g << 3];
            al[rt] = *(short8*)&Alo[(wr << 5) + (rt << 4) + cl][g << 3];
        }
        #pragma unroll
        for (int ct = 0; ct < 6; ++ct) {
            short8 bh = *(short8*)&Bhi[wc * 96 + (ct << 4) + cl][g << 3];
            short8 bl = *(short8*)&Blo[wc * 96 + (ct << 4) + cl][g << 3];
            #pragma unroll
            for (int rt = 0; rt < 2; ++rt) {
                acc[rt][ct] = __builtin_amdgcn_mfma_f32_16x16x32_bf16(ah[rt], bh, acc[rt][ct], 0, 0, 0);
                acc[rt][ct] = __builtin_amdgcn_mfma_f32_16x16x32_bf16(ah[rt], bl, acc[rt][ct], 0, 0, 0);
                acc[rt][ct] = __builtin_amdgcn_mfma_f32_16x16x32_bf16(al[rt], bh, acc[rt][ct], 0, 0, 0);
            }
        }
        __syncthreads();
    }

    // epilogue: RoPE (fp32) + hi/lo split stores
    #pragma unroll
    for (int rt = 0; rt < 2; ++rt) {
        #pragma unroll
        for (int ct = 0; ct < 6; ++ct) {
            int c = wc * 96 + (ct << 4) + cl;   // 0..191
            #pragma unroll
            for (int r = 0; r < 4; ++r) {
                int row = rb + (wr << 5) + (rt << 4) + (g << 2) + r;
                int s = row & (NS - 1);
                int b = row >> 12;
                float val = acc[rt][ct][r];
                if (c < 128) {
                    int d = c & 63;
                    int p = d >> 1;
                    float freq = exp2f(-(float)p * 0.41524101186091903f);
                    float theta = (float)s * freq;
                    float sn = sinf(theta), cs = cosf(theta);
                    float partner = __shfl_xor(val, 1);
                    float rot = (c & 1) ? fmaf(partner, sn, val * cs)
                                        : fmaf(-partner, sn, val * cs);
                    short hi = f2bf(rot);
                    short lo = f2bf(rot - bf2f(hi));
                    int off = row * ND + d;
                    if (c < 64) { qhi[off] = hi; qlo[off] = lo; }
                    else        { khi[off] = hi; klo[off] = lo; }
                } else {
                    int d = c - 128;
                    vt[((b << 6) + d) * NS + s] = f2bf(val);
                }
            }
        }
    }
}

// ---- kernel 3: causal flash attention — 1 wave/block, direct-global frags ----
// FIX vs round 5/6: Ps row width 40 -> 72. P columns run to 63; 40 overflowed
// (writes aliased into following rows => deterministic scrambled P => absmax 216.5).
__global__ __launch_bounds__(64) void attn_fused(
        const short* __restrict__ qhi, const short* __restrict__ qlo,
        const short* __restrict__ khi, const short* __restrict__ klo,
        const short* __restrict__ vt, float* __restrict__ outp) {
    __shared__ short Ps[16][72];               // 144B rows: 16B-aligned, validated in round 4
    const int lane = threadIdx.x;
    const int g = lane >> 4, cl = lane & 15;
    const int bid = blockIdx.x;
    const int b = (bid >> 1) & 3;
    const int t = 255 - (((bid >> 3) << 1) | (bid & 1));   // 0..255, heavy first
    const int qw = t << 4;
    const int rowb = b << 12;

    short8 qh[2], ql[2];
    #pragma unroll
    for (int ks = 0; ks < 2; ++ks) {
        int off = ((rowb + qw + cl) << 6) + (ks << 5) + (g << 3);
        qh[ks] = *(const short8*)(qhi + off);
        ql[ks] = *(const short8*)(qlo + off);
    }

    f32x4 o[4];
    float m[4], ls[4];
    #pragma unroll
    for (int i = 0; i < 4; ++i) {
        o[i] = (f32x4){0.f, 0.f, 0.f, 0.f};
        m[i] = -1e38f;
        ls[i] = 0.f;
    }

    const int nkv = (t >> 2) + 1;
    #pragma unroll 1
    for (int j = 0; j < nkv; ++j) {
        const int kv0 = j << 6;
        f32x4 sc[4];
        #pragma unroll
        for (int i = 0; i < 4; ++i) sc[i] = (f32x4){0.f, 0.f, 0.f, 0.f};

        #pragma unroll
        for (int ct = 0; ct < 4; ++ct) {
            const int roff = ((rowb + kv0 + (ct << 4) + cl) << 6) + (g << 3);
            short8 kh0 = *(const short8*)(khi + roff);
            short8 kh1 = *(const short8*)(khi + roff + 32);
            short8 kl0 = *(const short8*)(klo + roff);
            short8 kl1 = *(const short8*)(klo + roff + 32);
            sc[ct] = __builtin_amdgcn_mfma_f32_16x16x32_bf16(qh[0], kh0, sc[ct], 0, 0, 0);
            sc[ct] = __builtin_amdgcn_mfma_f32_16x16x32_bf16(qh[1], kh1, sc[ct], 0, 0, 0);
            sc[ct] = __builtin_amdgcn_mfma_f32_16x16x32_bf16(qh[0], kl0, sc[ct], 0, 0, 0);
            sc[ct] = __builtin_amdgcn_mfma_f32_16x16x32_bf16(qh[1], kl1, sc[ct], 0, 0, 0);
            sc[ct] = __builtin_amdgcn_mfma_f32_16x16x32_bf16(ql[0], kh0, sc[ct], 0, 0, 0);
            sc[ct] = __builtin_amdgcn_mfma_f32_16x16x32_bf16(ql[1], kh1, sc[ct], 0, 0, 0);
        }
        if (j == nkv - 1) {
            #pragma unroll
            for (int ct = 0; ct < 4; ++ct)
                #pragma unroll
                for (int r = 0; r < 4; ++r) {
                    int kv = kv0 + (ct << 4) + cl;
                    int q = qw + (g << 2) + r;
                    if (kv > q) sc[ct][r] = -1e30f;
                }
        }
        // online softmax over 16-lane row groups
        float pm[4];
        #pragma unroll
        for (int r = 0; r < 4; ++r)
            pm[r] = fmaxf(fmaxf(sc[0][r], sc[1][r]), fmaxf(sc[2][r], sc[3][r]));
        #pragma unroll
        for (int msk = 1; msk < 16; msk <<= 1)
            #pragma unroll
            for (int r = 0; r < 4; ++r)
                pm[r] = fmaxf(pm[r], __shfl_xor(pm[r], msk));
        float rs[4], ps[4];
        #pragma unroll
        for (int r = 0; r < 4; ++r) {
            float mn = fmaxf(m[r], pm[r]);
            rs[r] = __expf(m[r] - mn);
            m[r] = mn;
            ps[r] = 0.f;
        }
        #pragma unroll
        for (int ct = 0; ct < 4; ++ct)
            #pragma unroll
            for (int r = 0; r < 4; ++r) {
                float p = __expf(sc[ct][r] - m[r]);
                sc[ct][r] = p;
                ps[r] += p;
            }
        #pragma unroll
        for (int msk = 1; msk < 16; msk <<= 1)
            #pragma unroll
            for (int r = 0; r < 4; ++r)
                ps[r] += __shfl_xor(ps[r], msk);
        #pragma unroll
        for (int r = 0; r < 4; ++r) ls[r] = ls[r] * rs[r] + ps[r];
        #pragma unroll
        for (int dt = 0; dt < 4; ++dt)
            #pragma unroll
            for (int r = 0; r < 4; ++r) o[dt][r] *= rs[r];

        // P -> LDS, fence (free for 1-wave block; forces DS write->read order), then PV
        #pragma unroll
        for (int ct = 0; ct < 4; ++ct)
            #pragma unroll
            for (int r = 0; r < 4; ++r)
                Ps[(g << 2) + r][(ct << 4) + cl] = f2bf(sc[ct][r]);
        __syncthreads();
        #pragma unroll
        for (int ks = 0; ks < 2; ++ks) {
            short8 pa = *(short8*)&Ps[cl][(ks << 5) + (g << 3)];
            #pragma unroll
            for (int dt = 0; dt < 4; ++dt) {
                short8 vf = *(const short8*)(vt + (((b << 6) + (dt << 4) + cl) << 12)
                                                + kv0 + (ks << 5) + (g << 3));
                o[dt] = __builtin_amdgcn_mfma_f32_16x16x32_bf16(pa, vf, o[dt], 0, 0, 0);
            }
        }
        __syncthreads();
    }

    #pragma unroll
    for (int dt = 0; dt < 4; ++dt)
        #pragma unroll
        for (int r = 0; r < 4; ++r) {
            int row = rowb + qw + (g << 2) + r;
            outp[row * ND + (dt << 4) + cl] = o[dt][r] / ls[r];
        }
}

extern "C" void kernel_launch(void* const* d_in, const int* in_sizes, int n_in,
                              void* d_out, int out_size, void* d_ws, size_t ws_size,
                              hipStream_t stream) {
    const float* x  = (const float*)d_in[0];
    // d_in[1] = mask (int32 tril) -- causal structure known, unused
    const float* WQ = (const float*)d_in[2];
    const float* WK = (const float*)d_in[3];
    const float* WV = (const float*)d_in[4];

    const size_t need = 786432u + 4u * 2097152u + 2097152u;   // 11,272,192 B
    if (ws_size < need) return;

    char* ws = (char*)d_ws;
    short* wthi = (short*)(ws);                                  // 384 KB
    short* wtlo = (short*)(ws + 393216);
    short* qhi  = (short*)(ws + 786432);                         // 2 MB each
    short* qlo  = (short*)(ws + 786432 + 1 * 2097152);
    short* khi  = (short*)(ws + 786432 + 2 * 2097152);
    short* klo  = (short*)(ws + 786432 + 3 * 2097152);
    short* vt   = (short*)(ws + 786432 + 4 * 2097152);           // V^T [B][64][4096]

    prep_wt<<<768, 256, 0, stream>>>(WQ, WK, WV, wthi, wtlo);
    proj_rope<<<256, 256, 0, stream>>>(x, wthi, wtlo, qhi, qlo, khi, klo, vt);
    attn_fused<<<1024, 64, 0, stream>>>(qhi, qlo, khi, klo, vt, (float*)d_out);
}

// Round 8
// 215.240 us; speedup vs baseline: 1.4507x; 1.4507x over previous
//
#include <hip/hip_runtime.h>

typedef short short8  __attribute__((ext_vector_type(8)));
typedef short short4v __attribute__((ext_vector_type(4)));
typedef float f32x4   __attribute__((ext_vector_type(4)));

#define NB 4
#define NS 4096
#define NE 1024
#define ND 64

__device__ __forceinline__ short f2bf(float f) {
    unsigned u = __builtin_bit_cast(unsigned, f);
    u = (u + 0x7FFFu + ((u >> 16) & 1u)) >> 16;
    return (short)u;
}
__device__ __forceinline__ float bf2f(short s) {
    unsigned u = ((unsigned)(unsigned short)s) << 16;
    return __builtin_bit_cast(float, u);
}

// ---- kernel 1: W transpose + concat + bf16 hi/lo split (scale folded into W_Q) ----
__global__ void prep_wt(const float* __restrict__ WQ, const float* __restrict__ WK,
                        const float* __restrict__ WV,
                        short* __restrict__ wthi, short* __restrict__ wtlo) {
    int idx = blockIdx.x * 256 + threadIdx.x;     // 192*1024
    if (idx >= 192 * NE) return;
    int n = idx >> 10, k = idx & (NE - 1);
    int sel = n >> 6, d = n & 63;
    const float* W = (sel == 0) ? WQ : (sel == 1 ? WK : WV);
    float v = W[k * ND + d];
    if (sel == 0) v *= 0.125f;                    // 1/sqrt(64), exact power of 2
    short hi = f2bf(v);
    short lo = f2bf(v - bf2f(hi));
    wthi[idx] = hi;
    wtlo[idx] = lo;
}

// ---- kernel 2: QKV projection (LDS-staged, KNOWN GOOD round-4 version, unchanged) ----
__global__ __launch_bounds__(256) void proj_rope(
        const float* __restrict__ x,
        const short* __restrict__ wthi, const short* __restrict__ wtlo,
        short* __restrict__ qhi, short* __restrict__ qlo,
        short* __restrict__ khi, short* __restrict__ klo,
        short* __restrict__ vt) {
    __shared__ short Ahi[64][40], Alo[64][40];
    __shared__ short Bhi[192][40], Blo[192][40];
    const int tid = threadIdx.x;
    const int lane = tid & 63, wid = tid >> 6;
    const int wr = wid >> 1, wc = wid & 1;
    const int g = lane >> 4, cl = lane & 15;
    const int rb = blockIdx.x * 64;

    f32x4 zero4 = {0.f, 0.f, 0.f, 0.f};
    f32x4 acc[2][6];
    #pragma unroll
    for (int i = 0; i < 2; ++i)
        #pragma unroll
        for (int j = 0; j < 6; ++j) acc[i][j] = zero4;

    const int arow = tid >> 3, acol = (tid & 7) << 2;
    const int bn = tid >> 2, bk = (tid & 3) << 3;

    for (int k0 = 0; k0 < NE; k0 += 32) {
        #pragma unroll
        for (int i = 0; i < 2; ++i) {
            int r = arow + (i << 5);
            const float4 v = *(const float4*)(x + (rb + r) * NE + k0 + acol);
            float vv[4] = {v.x, v.y, v.z, v.w};
            short4v hv, lv;
            #pragma unroll
            for (int q = 0; q < 4; ++q) {
                short h = f2bf(vv[q]);
                hv[q] = h;
                lv[q] = f2bf(vv[q] - bf2f(h));
            }
            *(short4v*)&Ahi[r][acol] = hv;
            *(short4v*)&Alo[r][acol] = lv;
        }
        #pragma unroll
        for (int i = 0; i < 3; ++i) {
            int n = bn + (i << 6);
            *(short8*)&Bhi[n][bk] = *(const short8*)(wthi + n * NE + k0 + bk);
            *(short8*)&Blo[n][bk] = *(const short8*)(wtlo + n * NE + k0 + bk);
        }
        __syncthreads();
        short8 ah[2], al[2];
        #pragma unroll
        for (int rt = 0; rt < 2; ++rt) {
            ah[rt] = *(short8*)&Ahi[(wr << 5) + (rt << 4) + cl][g << 3];
            al[rt] = *(short8*)&Alo[(wr << 5) + (rt << 4) + cl][g << 3];
        }
        #pragma unroll
        for (int ct = 0; ct < 6; ++ct) {
            short8 bh = *(short8*)&Bhi[wc * 96 + (ct << 4) + cl][g << 3];
            short8 bl = *(short8*)&Blo[wc * 96 + (ct << 4) + cl][g << 3];
            #pragma unroll
            for (int rt = 0; rt < 2; ++rt) {
                acc[rt][ct] = __builtin_amdgcn_mfma_f32_16x16x32_bf16(ah[rt], bh, acc[rt][ct], 0, 0, 0);
                acc[rt][ct] = __builtin_amdgcn_mfma_f32_16x16x32_bf16(ah[rt], bl, acc[rt][ct], 0, 0, 0);
                acc[rt][ct] = __builtin_amdgcn_mfma_f32_16x16x32_bf16(al[rt], bh, acc[rt][ct], 0, 0, 0);
            }
        }
        __syncthreads();
    }

    #pragma unroll
    for (int rt = 0; rt < 2; ++rt) {
        #pragma unroll
        for (int ct = 0; ct < 6; ++ct) {
            int c = wc * 96 + (ct << 4) + cl;   // 0..191
            #pragma unroll
            for (int r = 0; r < 4; ++r) {
                int row = rb + (wr << 5) + (rt << 4) + (g << 2) + r;
                int s = row & (NS - 1);
                int b = row >> 12;
                float val = acc[rt][ct][r];
                if (c < 128) {
                    int d = c & 63;
                    int p = d >> 1;
                    float freq = exp2f(-(float)p * 0.41524101186091903f);
                    float theta = (float)s * freq;
                    float sn = sinf(theta), cs = cosf(theta);
                    float partner = __shfl_xor(val, 1);
                    float rot = (c & 1) ? fmaf(partner, sn, val * cs)
                                        : fmaf(-partner, sn, val * cs);
                    short hi = f2bf(rot);
                    short lo = f2bf(rot - bf2f(hi));
                    int off = row * ND + d;
                    if (c < 64) { qhi[off] = hi; qlo[off] = lo; }
                    else        { khi[off] = hi; klo[off] = lo; }
                } else {
                    int d = c - 128;
                    vt[((b << 6) + d) * NS + s] = f2bf(val);
                }
            }
        }
    }
}

// ---- kernel 3: causal flash attention — 4 KV-split waves per 16-row q-tile + flash-combine ----
// Per-wave pipeline is byte-identical to validated round-7; wave w takes kv-tiles j≡w (mod 4).
__global__ __launch_bounds__(256) void attn_fused(
        const short* __restrict__ qhi, const short* __restrict__ qlo,
        const short* __restrict__ khi, const short* __restrict__ klo,
        const short* __restrict__ vt, float* __restrict__ outp) {
    __shared__ short Ps[4][16][72];            // per-wave P tile (validated width)
    __shared__ float Co[4][16][66];            // partial O, +2 pad for bank spread
    __shared__ float Cm[4][16], Cls[4][16];
    const int tid = threadIdx.x;
    const int lane = tid & 63, w = tid >> 6;
    const int g = lane >> 4, cl = lane & 15;
    const int bid = blockIdx.x;
    const int b = (bid >> 1) & 3;                          // XCD-pair -> batch (validated: FETCH 8MB)
    const int t = 255 - (((bid >> 3) << 1) | (bid & 1));   // heavy tiles first
    const int qw = t << 4;
    const int rowb = b << 12;

    short8 qh[2], ql[2];
    #pragma unroll
    for (int ks = 0; ks < 2; ++ks) {
        int off = ((rowb + qw + cl) << 6) + (ks << 5) + (g << 3);
        qh[ks] = *(const short8*)(qhi + off);
        ql[ks] = *(const short8*)(qlo + off);
    }

    f32x4 o[4];
    float m[4], ls[4];
    #pragma unroll
    for (int i = 0; i < 4; ++i) {
        o[i] = (f32x4){0.f, 0.f, 0.f, 0.f};
        m[i] = -1e38f;
        ls[i] = 0.f;
    }

    const int nkv = (t >> 2) + 1;
    #pragma unroll 1
    for (int j = w; j < nkv; j += 4) {         // strided KV-split across the 4 waves
        const int kv0 = j << 6;
        f32x4 sc[4];
        #pragma unroll
        for (int i = 0; i < 4; ++i) sc[i] = (f32x4){0.f, 0.f, 0.f, 0.f};

        #pragma unroll
        for (int ct = 0; ct < 4; ++ct) {
            const int roff = ((rowb + kv0 + (ct << 4) + cl) << 6) + (g << 3);
            short8 kh0 = *(const short8*)(khi + roff);
            short8 kh1 = *(const short8*)(khi + roff + 32);
            short8 kl0 = *(const short8*)(klo + roff);
            short8 kl1 = *(const short8*)(klo + roff + 32);
            sc[ct] = __builtin_amdgcn_mfma_f32_16x16x32_bf16(qh[0], kh0, sc[ct], 0, 0, 0);
            sc[ct] = __builtin_amdgcn_mfma_f32_16x16x32_bf16(qh[1], kh1, sc[ct], 0, 0, 0);
            sc[ct] = __builtin_amdgcn_mfma_f32_16x16x32_bf16(qh[0], kl0, sc[ct], 0, 0, 0);
            sc[ct] = __builtin_amdgcn_mfma_f32_16x16x32_bf16(qh[1], kl1, sc[ct], 0, 0, 0);
            sc[ct] = __builtin_amdgcn_mfma_f32_16x16x32_bf16(ql[0], kh0, sc[ct], 0, 0, 0);
            sc[ct] = __builtin_amdgcn_mfma_f32_16x16x32_bf16(ql[1], kh1, sc[ct], 0, 0, 0);
        }
        if (j == nkv - 1) {
            #pragma unroll
            for (int ct = 0; ct < 4; ++ct)
                #pragma unroll
                for (int r = 0; r < 4; ++r) {
                    int kv = kv0 + (ct << 4) + cl;
                    int q = qw + (g << 2) + r;
                    if (kv > q) sc[ct][r] = -1e30f;
                }
        }
        float pm[4];
        #pragma unroll
        for (int r = 0; r < 4; ++r)
            pm[r] = fmaxf(fmaxf(sc[0][r], sc[1][r]), fmaxf(sc[2][r], sc[3][r]));
        #pragma unroll
        for (int msk = 1; msk < 16; msk <<= 1)
            #pragma unroll
            for (int r = 0; r < 4; ++r)
                pm[r] = fmaxf(pm[r], __shfl_xor(pm[r], msk));
        float rs[4], ps[4];
        #pragma unroll
        for (int r = 0; r < 4; ++r) {
            float mn = fmaxf(m[r], pm[r]);
            rs[r] = __expf(m[r] - mn);
            m[r] = mn;
            ps[r] = 0.f;
        }
        #pragma unroll
        for (int ct = 0; ct < 4; ++ct)
            #pragma unroll
            for (int r = 0; r < 4; ++r) {
                float p = __expf(sc[ct][r] - m[r]);
                sc[ct][r] = p;
                ps[r] += p;
            }
        #pragma unroll
        for (int msk = 1; msk < 16; msk <<= 1)
            #pragma unroll
            for (int r = 0; r < 4; ++r)
                ps[r] += __shfl_xor(ps[r], msk);
        #pragma unroll
        for (int r = 0; r < 4; ++r) ls[r] = ls[r] * rs[r] + ps[r];
        #pragma unroll
        for (int dt = 0; dt < 4; ++dt)
            #pragma unroll
            for (int r = 0; r < 4; ++r) o[dt][r] *= rs[r];

        // P -> per-wave LDS slice; same-wave RAW (no barrier; validated round 4)
        #pragma unroll
        for (int ct = 0; ct < 4; ++ct)
            #pragma unroll
            for (int r = 0; r < 4; ++r)
                Ps[w][(g << 2) + r][(ct << 4) + cl] = f2bf(sc[ct][r]);
        #pragma unroll
        for (int ks = 0; ks < 2; ++ks) {
            short8 pa = *(short8*)&Ps[w][cl][(ks << 5) + (g << 3)];
            #pragma unroll
            for (int dt = 0; dt < 4; ++dt) {
                short8 vf = *(const short8*)(vt + (((b << 6) + (dt << 4) + cl) << 12)
                                                + kv0 + (ks << 5) + (g << 3));
                o[dt] = __builtin_amdgcn_mfma_f32_16x16x32_bf16(pa, vf, o[dt], 0, 0, 0);
            }
        }
    }

    // publish partials (idle waves publish m=-1e38, ls=0 -> zero weight)
    #pragma unroll
    for (int r = 0; r < 4; ++r)
        if (cl == 0) { Cm[w][(g << 2) + r] = m[r]; Cls[w][(g << 2) + r] = ls[r]; }
    #pragma unroll
    for (int dt = 0; dt < 4; ++dt)
        #pragma unroll
        for (int r = 0; r < 4; ++r)
            Co[w][(g << 2) + r][(dt << 4) + cl] = o[dt][r];
    __syncthreads();

    // exact flash-combine by wave 0
    if (w == 0) {
        #pragma unroll
        for (int r = 0; r < 4; ++r) {
            const int row = (g << 2) + r;
            float M = fmaxf(fmaxf(Cm[0][row], Cm[1][row]), fmaxf(Cm[2][row], Cm[3][row]));
            float e0 = __expf(Cm[0][row] - M), e1 = __expf(Cm[1][row] - M);
            float e2 = __expf(Cm[2][row] - M), e3 = __expf(Cm[3][row] - M);
            float L = Cls[0][row] * e0 + Cls[1][row] * e1 + Cls[2][row] * e2 + Cls[3][row] * e3;
            float inv = 1.f / L;
            #pragma unroll
            for (int dt = 0; dt < 4; ++dt) {
                int d = (dt << 4) + cl;
                float O = Co[0][row][d] * e0 + Co[1][row][d] * e1
                        + Co[2][row][d] * e2 + Co[3][row][d] * e3;
                outp[(rowb + qw + row) * ND + d] = O * inv;
            }
        }
    }
}

extern "C" void kernel_launch(void* const* d_in, const int* in_sizes, int n_in,
                              void* d_out, int out_size, void* d_ws, size_t ws_size,
                              hipStream_t stream) {
    const float* x  = (const float*)d_in[0];
    // d_in[1] = mask (int32 tril) -- causal structure known, unused
    const float* WQ = (const float*)d_in[2];
    const float* WK = (const float*)d_in[3];
    const float* WV = (const float*)d_in[4];

    const size_t need = 786432u + 4u * 2097152u + 2097152u;   // 11,272,192 B
    if (ws_size < need) return;

    char* ws = (char*)d_ws;
    short* wthi = (short*)(ws);                                  // 384 KB
    short* wtlo = (short*)(ws + 393216);
    short* qhi  = (short*)(ws + 786432);                         // 2 MB each
    short* qlo  = (short*)(ws + 786432 + 1 * 2097152);
    short* khi  = (short*)(ws + 786432 + 2 * 2097152);
    short* klo  = (short*)(ws + 786432 + 3 * 2097152);
    short* vt   = (short*)(ws + 786432 + 4 * 2097152);           // V^T [B][64][4096]

    prep_wt<<<768, 256, 0, stream>>>(WQ, WK, WV, wthi, wtlo);
    proj_rope<<<256, 256, 0, stream>>>(x, wthi, wtlo, qhi, qlo, khi, klo, vt);
    attn_fused<<<1024, 256, 0, stream>>>(qhi, qlo, khi, klo, vt, (float*)d_out);
}

// Round 9
// 202.163 us; speedup vs baseline: 1.5446x; 1.0647x over previous
//
#include <hip/hip_runtime.h>

typedef short short8  __attribute__((ext_vector_type(8)));
typedef float f32x4   __attribute__((ext_vector_type(4)));

#define NB 4
#define NS 4096
#define NE 1024
#define ND 64

__device__ __forceinline__ short f2bf(float f) {
    unsigned u = __builtin_bit_cast(unsigned, f);
    u = (u + 0x7FFFu + ((u >> 16) & 1u)) >> 16;
    return (short)u;
}
__device__ __forceinline__ float bf2f(short s) {
    unsigned u = ((unsigned)(unsigned short)s) << 16;
    return __builtin_bit_cast(float, u);
}

// ---- kernel 1: W transpose + concat + bf16 hi/lo split (scale folded into W_Q) ----
__global__ void prep_wt(const float* __restrict__ WQ, const float* __restrict__ WK,
                        const float* __restrict__ WV,
                        short* __restrict__ wthi, short* __restrict__ wtlo) {
    int idx = blockIdx.x * 256 + threadIdx.x;     // 192*1024
    if (idx >= 192 * NE) return;
    int n = idx >> 10, k = idx & (NE - 1);
    int sel = n >> 6, d = n & 63;
    const float* W = (sel == 0) ? WQ : (sel == 1 ? WK : WV);
    float v = W[k * ND + d];
    if (sel == 0) v *= 0.125f;                    // 1/sqrt(64), exact power of 2
    short hi = f2bf(v);
    short lo = f2bf(v - bf2f(hi));
    wthi[idx] = hi;
    wtlo[idx] = lo;
}

// ---- kernel 2: QKV projection — barrier-free, LDS-free, 1 wave/block, 32x48 tiles ----
// 2048 blocks x 64 thr = 8 waves/CU. A-frags direct from x, B-frags from L2-resident wt.
// Fragment addressing is a 1:1 transcription of the validated round-4 LDS pattern.
__global__ __launch_bounds__(64) void proj_rope(
        const float* __restrict__ x,
        const short* __restrict__ wthi, const short* __restrict__ wtlo,
        short* __restrict__ qhi, short* __restrict__ qlo,
        short* __restrict__ khi, short* __restrict__ klo,
        short* __restrict__ vt) {
    const int lane = threadIdx.x;
    const int g = lane >> 4, cl = lane & 15;
    const int bid = blockIdx.x;
    const int rb = (bid >> 2) << 5;               // 32-row tile
    const int c0 = (bid & 3) * 48;                // 48-col tile (0,48,96,144)

    f32x4 acc[2][3];
    #pragma unroll
    for (int i = 0; i < 2; ++i)
        #pragma unroll
        for (int j = 0; j < 3; ++j) acc[i][j] = (f32x4){0.f, 0.f, 0.f, 0.f};

    const float* xb  = x    + (size_t)(rb + cl) * NE + (g << 3);
    const short* bh0 = wthi + (size_t)(c0 + cl) * NE + (g << 3);
    const short* bl0 = wtlo + (size_t)(c0 + cl) * NE + (g << 3);

    #pragma unroll 2
    for (int k0 = 0; k0 < NE; k0 += 32) {
        short8 ah[2], al[2];
        #pragma unroll
        for (int rt = 0; rt < 2; ++rt) {
            const float* xp = xb + (rt << 4) * NE + k0;
            float4 v0 = *(const float4*)xp;
            float4 v1 = *(const float4*)(xp + 4);
            float vv[8] = {v0.x, v0.y, v0.z, v0.w, v1.x, v1.y, v1.z, v1.w};
            #pragma unroll
            for (int q = 0; q < 8; ++q) {
                short h = f2bf(vv[q]);
                ah[rt][q] = h;
                al[rt][q] = f2bf(vv[q] - bf2f(h));
            }
        }
        #pragma unroll
        for (int ct = 0; ct < 3; ++ct) {
            short8 bh = *(const short8*)(bh0 + (ct << 4) * NE + k0);
            short8 bl = *(const short8*)(bl0 + (ct << 4) * NE + k0);
            #pragma unroll
            for (int rt = 0; rt < 2; ++rt) {
                acc[rt][ct] = __builtin_amdgcn_mfma_f32_16x16x32_bf16(ah[rt], bh, acc[rt][ct], 0, 0, 0);
                acc[rt][ct] = __builtin_amdgcn_mfma_f32_16x16x32_bf16(ah[rt], bl, acc[rt][ct], 0, 0, 0);
                acc[rt][ct] = __builtin_amdgcn_mfma_f32_16x16x32_bf16(al[rt], bh, acc[rt][ct], 0, 0, 0);
            }
        }
    }

    // epilogue: RoPE (fp32) + hi/lo split stores — identical logic to validated round 4
    #pragma unroll
    for (int rt = 0; rt < 2; ++rt) {
        #pragma unroll
        for (int ct = 0; ct < 3; ++ct) {
            int c = c0 + (ct << 4) + cl;          // 0..191
            #pragma unroll
            for (int r = 0; r < 4; ++r) {
                int row = rb + (rt << 4) + (g << 2) + r;
                int s = row & (NS - 1);
                int b = row >> 12;
                float val = acc[rt][ct][r];
                if (c < 128) {
                    int d = c & 63;
                    int p = d >> 1;
                    float freq = exp2f(-(float)p * 0.41524101186091903f);
                    float theta = (float)s * freq;
                    float sn = sinf(theta), cs = cosf(theta);
                    float partner = __shfl_xor(val, 1);
                    float rot = (c & 1) ? fmaf(partner, sn, val * cs)
                                        : fmaf(-partner, sn, val * cs);
                    short hi = f2bf(rot);
                    short lo = f2bf(rot - bf2f(hi));
                    int off = row * ND + d;
                    if (c < 64) { qhi[off] = hi; qlo[off] = lo; }
                    else        { khi[off] = hi; klo[off] = lo; }
                } else {
                    int d = c - 128;
                    vt[((b << 6) + d) * NS + s] = f2bf(val);
                }
            }
        }
    }
}

// ---- kernel 3: causal flash attention — UNCHANGED from round 8 (PASS @ ~90us) ----
__global__ __launch_bounds__(256) void attn_fused(
        const short* __restrict__ qhi, const short* __restrict__ qlo,
        const short* __restrict__ khi, const short* __restrict__ klo,
        const short* __restrict__ vt, float* __restrict__ outp) {
    __shared__ short Ps[4][16][72];
    __shared__ float Co[4][16][66];
    __shared__ float Cm[4][16], Cls[4][16];
    const int tid = threadIdx.x;
    const int lane = tid & 63, w = tid >> 6;
    const int g = lane >> 4, cl = lane & 15;
    const int bid = blockIdx.x;
    const int b = (bid >> 1) & 3;
    const int t = 255 - (((bid >> 3) << 1) | (bid & 1));
    const int qw = t << 4;
    const int rowb = b << 12;

    short8 qh[2], ql[2];
    #pragma unroll
    for (int ks = 0; ks < 2; ++ks) {
        int off = ((rowb + qw + cl) << 6) + (ks << 5) + (g << 3);
        qh[ks] = *(const short8*)(qhi + off);
        ql[ks] = *(const short8*)(qlo + off);
    }

    f32x4 o[4];
    float m[4], ls[4];
    #pragma unroll
    for (int i = 0; i < 4; ++i) {
        o[i] = (f32x4){0.f, 0.f, 0.f, 0.f};
        m[i] = -1e38f;
        ls[i] = 0.f;
    }

    const int nkv = (t >> 2) + 1;
    #pragma unroll 1
    for (int j = w; j < nkv; j += 4) {
        const int kv0 = j << 6;
        f32x4 sc[4];
        #pragma unroll
        for (int i = 0; i < 4; ++i) sc[i] = (f32x4){0.f, 0.f, 0.f, 0.f};

        #pragma unroll
        for (int ct = 0; ct < 4; ++ct) {
            const int roff = ((rowb + kv0 + (ct << 4) + cl) << 6) + (g << 3);
            short8 kh0 = *(const short8*)(khi + roff);
            short8 kh1 = *(const short8*)(khi + roff + 32);
            short8 kl0 = *(const short8*)(klo + roff);
            short8 kl1 = *(const short8*)(klo + roff + 32);
            sc[ct] = __builtin_amdgcn_mfma_f32_16x16x32_bf16(qh[0], kh0, sc[ct], 0, 0, 0);
            sc[ct] = __builtin_amdgcn_mfma_f32_16x16x32_bf16(qh[1], kh1, sc[ct], 0, 0, 0);
            sc[ct] = __builtin_amdgcn_mfma_f32_16x16x32_bf16(qh[0], kl0, sc[ct], 0, 0, 0);
            sc[ct] = __builtin_amdgcn_mfma_f32_16x16x32_bf16(qh[1], kl1, sc[ct], 0, 0, 0);
            sc[ct] = __builtin_amdgcn_mfma_f32_16x16x32_bf16(ql[0], kh0, sc[ct], 0, 0, 0);
            sc[ct] = __builtin_amdgcn_mfma_f32_16x16x32_bf16(ql[1], kh1, sc[ct], 0, 0, 0);
        }
        if (j == nkv - 1) {
            #pragma unroll
            for (int ct = 0; ct < 4; ++ct)
                #pragma unroll
                for (int r = 0; r < 4; ++r) {
                    int kv = kv0 + (ct << 4) + cl;
                    int q = qw + (g << 2) + r;
                    if (kv > q) sc[ct][r] = -1e30f;
                }
        }
        float pm[4];
        #pragma unroll
        for (int r = 0; r < 4; ++r)
            pm[r] = fmaxf(fmaxf(sc[0][r], sc[1][r]), fmaxf(sc[2][r], sc[3][r]));
        #pragma unroll
        for (int msk = 1; msk < 16; msk <<= 1)
            #pragma unroll
            for (int r = 0; r < 4; ++r)
                pm[r] = fmaxf(pm[r], __shfl_xor(pm[r], msk));
        float rs[4], ps[4];
        #pragma unroll
        for (int r = 0; r < 4; ++r) {
            float mn = fmaxf(m[r], pm[r]);
            rs[r] = __expf(m[r] - mn);
            m[r] = mn;
            ps[r] = 0.f;
        }
        #pragma unroll
        for (int ct = 0; ct < 4; ++ct)
            #pragma unroll
            for (int r = 0; r < 4; ++r) {
                float p = __expf(sc[ct][r] - m[r]);
                sc[ct][r] = p;
                ps[r] += p;
            }
        #pragma unroll
        for (int msk = 1; msk < 16; msk <<= 1)
            #pragma unroll
            for (int r = 0; r < 4; ++r)
                ps[r] += __shfl_xor(ps[r], msk);
        #pragma unroll
        for (int r = 0; r < 4; ++r) ls[r] = ls[r] * rs[r] + ps[r];
        #pragma unroll
        for (int dt = 0; dt < 4; ++dt)
            #pragma unroll
            for (int r = 0; r < 4; ++r) o[dt][r] *= rs[r];

        #pragma unroll
        for (int ct = 0; ct < 4; ++ct)
            #pragma unroll
            for (int r = 0; r < 4; ++r)
                Ps[w][(g << 2) + r][(ct << 4) + cl] = f2bf(sc[ct][r]);
        #pragma unroll
        for (int ks = 0; ks < 2; ++ks) {
            short8 pa = *(short8*)&Ps[w][cl][(ks << 5) + (g << 3)];
            #pragma unroll
            for (int dt = 0; dt < 4; ++dt) {
                short8 vf = *(const short8*)(vt + (((b << 6) + (dt << 4) + cl) << 12)
                                                + kv0 + (ks << 5) + (g << 3));
                o[dt] = __builtin_amdgcn_mfma_f32_16x16x32_bf16(pa, vf, o[dt], 0, 0, 0);
            }
        }
    }

    #pragma unroll
    for (int r = 0; r < 4; ++r)
        if (cl == 0) { Cm[w][(g << 2) + r] = m[r]; Cls[w][(g << 2) + r] = ls[r]; }
    #pragma unroll
    for (int dt = 0; dt < 4; ++dt)
        #pragma unroll
        for (int r = 0; r < 4; ++r)
            Co[w][(g << 2) + r][(dt << 4) + cl] = o[dt][r];
    __syncthreads();

    if (w == 0) {
        #pragma unroll
        for (int r = 0; r < 4; ++r) {
            const int row = (g << 2) + r;
            float M = fmaxf(fmaxf(Cm[0][row], Cm[1][row]), fmaxf(Cm[2][row], Cm[3][row]));
            float e0 = __expf(Cm[0][row] - M), e1 = __expf(Cm[1][row] - M);
            float e2 = __expf(Cm[2][row] - M), e3 = __expf(Cm[3][row] - M);
            float L = Cls[0][row] * e0 + Cls[1][row] * e1 + Cls[2][row] * e2 + Cls[3][row] * e3;
            float inv = 1.f / L;
            #pragma unroll
            for (int dt = 0; dt < 4; ++dt) {
                int d = (dt << 4) + cl;
                float O = Co[0][row][d] * e0 + Co[1][row][d] * e1
                        + Co[2][row][d] * e2 + Co[3][row][d] * e3;
                outp[(rowb + qw + row) * ND + d] = O * inv;
            }
        }
    }
}

extern "C" void kernel_launch(void* const* d_in, const int* in_sizes, int n_in,
                              void* d_out, int out_size, void* d_ws, size_t ws_size,
                              hipStream_t stream) {
    const float* x  = (const float*)d_in[0];
    // d_in[1] = mask (int32 tril) -- causal structure known, unused
    const float* WQ = (const float*)d_in[2];
    const float* WK = (const float*)d_in[3];
    const float* WV = (const float*)d_in[4];

    const size_t need = 786432u + 4u * 2097152u + 2097152u;   // 11,272,192 B
    if (ws_size < need) return;

    char* ws = (char*)d_ws;
    short* wthi = (short*)(ws);                                  // 384 KB
    short* wtlo = (short*)(ws + 393216);
    short* qhi  = (short*)(ws + 786432);                         // 2 MB each
    short* qlo  = (short*)(ws + 786432 + 1 * 2097152);
    short* khi  = (short*)(ws + 786432 + 2 * 2097152);
    short* klo  = (short*)(ws + 786432 + 3 * 2097152);
    short* vt   = (short*)(ws + 786432 + 4 * 2097152);           // V^T [B][64][4096]

    prep_wt<<<768, 256, 0, stream>>>(WQ, WK, WV, wthi, wtlo);
    proj_rope<<<2048, 64, 0, stream>>>(x, wthi, wtlo, qhi, qlo, khi, klo, vt);
    attn_fused<<<1024, 256, 0, stream>>>(qhi, qlo, khi, klo, vt, (float*)d_out);
}

// Round 10
// 193.142 us; speedup vs baseline: 1.6167x; 1.0467x over previous
//
#include <hip/hip_runtime.h>

typedef short short8  __attribute__((ext_vector_type(8)));
typedef short short4v __attribute__((ext_vector_type(4)));
typedef float f32x4   __attribute__((ext_vector_type(4)));

#define NB 4
#define NS 4096
#define NE 1024
#define ND 64

__device__ __forceinline__ short f2bf(float f) {
    unsigned u = __builtin_bit_cast(unsigned, f);
    u = (u + 0x7FFFu + ((u >> 16) & 1u)) >> 16;
    return (short)u;
}
__device__ __forceinline__ float bf2f(short s) {
    unsigned u = ((unsigned)(unsigned short)s) << 16;
    return __builtin_bit_cast(float, u);
}

// ---- kernel 1: W transpose + concat + bf16 hi/lo split (scale folded into W_Q) ----
__global__ void prep_wt(const float* __restrict__ WQ, const float* __restrict__ WK,
                        const float* __restrict__ WV,
                        short* __restrict__ wthi, short* __restrict__ wtlo) {
    int idx = blockIdx.x * 256 + threadIdx.x;     // 192*1024
    if (idx >= 192 * NE) return;
    int n = idx >> 10, k = idx & (NE - 1);
    int sel = n >> 6, d = n & 63;
    const float* W = (sel == 0) ? WQ : (sel == 1 ? WK : WV);
    float v = W[k * ND + d];
    if (sel == 0) v *= 0.125f;                    // 1/sqrt(64), exact power of 2
    short hi = f2bf(v);
    short lo = f2bf(v - bf2f(hi));
    wthi[idx] = hi;
    wtlo[idx] = lo;
}

// ---- kernel 2: QKV projection — UNCHANGED from round 9 ----
__global__ __launch_bounds__(64) void proj_rope(
        const float* __restrict__ x,
        const short* __restrict__ wthi, const short* __restrict__ wtlo,
        short* __restrict__ qhi, short* __restrict__ qlo,
        short* __restrict__ khi, short* __restrict__ klo,
        short* __restrict__ vt) {
    const int lane = threadIdx.x;
    const int g = lane >> 4, cl = lane & 15;
    const int bid = blockIdx.x;
    const int rb = (bid >> 2) << 5;               // 32-row tile
    const int c0 = (bid & 3) * 48;                // 48-col tile

    f32x4 acc[2][3];
    #pragma unroll
    for (int i = 0; i < 2; ++i)
        #pragma unroll
        for (int j = 0; j < 3; ++j) acc[i][j] = (f32x4){0.f, 0.f, 0.f, 0.f};

    const float* xb  = x    + (size_t)(rb + cl) * NE + (g << 3);
    const short* bh0 = wthi + (size_t)(c0 + cl) * NE + (g << 3);
    const short* bl0 = wtlo + (size_t)(c0 + cl) * NE + (g << 3);

    #pragma unroll 2
    for (int k0 = 0; k0 < NE; k0 += 32) {
        short8 ah[2], al[2];
        #pragma unroll
        for (int rt = 0; rt < 2; ++rt) {
            const float* xp = xb + (rt << 4) * NE + k0;
            float4 v0 = *(const float4*)xp;
            float4 v1 = *(const float4*)(xp + 4);
            float vv[8] = {v0.x, v0.y, v0.z, v0.w, v1.x, v1.y, v1.z, v1.w};
            #pragma unroll
            for (int q = 0; q < 8; ++q) {
                short h = f2bf(vv[q]);
                ah[rt][q] = h;
                al[rt][q] = f2bf(vv[q] - bf2f(h));
            }
        }
        #pragma unroll
        for (int ct = 0; ct < 3; ++ct) {
            short8 bh = *(const short8*)(bh0 + (ct << 4) * NE + k0);
            short8 bl = *(const short8*)(bl0 + (ct << 4) * NE + k0);
            #pragma unroll
            for (int rt = 0; rt < 2; ++rt) {
                acc[rt][ct] = __builtin_amdgcn_mfma_f32_16x16x32_bf16(ah[rt], bh, acc[rt][ct], 0, 0, 0);
                acc[rt][ct] = __builtin_amdgcn_mfma_f32_16x16x32_bf16(ah[rt], bl, acc[rt][ct], 0, 0, 0);
                acc[rt][ct] = __builtin_amdgcn_mfma_f32_16x16x32_bf16(al[rt], bh, acc[rt][ct], 0, 0, 0);
            }
        }
    }

    #pragma unroll
    for (int rt = 0; rt < 2; ++rt) {
        #pragma unroll
        for (int ct = 0; ct < 3; ++ct) {
            int c = c0 + (ct << 4) + cl;
            #pragma unroll
            for (int r = 0; r < 4; ++r) {
                int row = rb + (rt << 4) + (g << 2) + r;
                int s = row & (NS - 1);
                int b = row >> 12;
                float val = acc[rt][ct][r];
                if (c < 128) {
                    int d = c & 63;
                    int p = d >> 1;
                    float freq = exp2f(-(float)p * 0.41524101186091903f);
                    float theta = (float)s * freq;
                    float sn = sinf(theta), cs = cosf(theta);
                    float partner = __shfl_xor(val, 1);
                    float rot = (c & 1) ? fmaf(partner, sn, val * cs)
                                        : fmaf(-partner, sn, val * cs);
                    short hi = f2bf(rot);
                    short lo = f2bf(rot - bf2f(hi));
                    int off = row * ND + d;
                    if (c < 64) { qhi[off] = hi; qlo[off] = lo; }
                    else        { khi[off] = hi; klo[off] = lo; }
                } else {
                    int d = c - 128;
                    vt[((b << 6) + d) * NS + s] = f2bf(val);
                }
            }
        }
    }
}

// ---- kernel 3: causal flash attention — swapped-operand QK (lane-local softmax) ----
// mfma(K,Q): sc lane layout S[kv=(ct<<4)+(g<<2)+r][q=cl]. Same loads as round 9.
// Softmax: per-lane 16-max tree + 2 cross-g shfls; ls as per-lane partial, summed at end.
// P contract Ps[w][q][kv] preserved => PV path / combine identical to round 9.
__global__ __launch_bounds__(256) void attn_fused(
        const short* __restrict__ qhi, const short* __restrict__ qlo,
        const short* __restrict__ khi, const short* __restrict__ klo,
        const short* __restrict__ vt, float* __restrict__ outp) {
    __shared__ short Ps[4][16][72];
    __shared__ float Co[4][16][66];
    __shared__ float Cm[4][16], Cls[4][16];
    const int tid = threadIdx.x;
    const int lane = tid & 63, w = tid >> 6;
    const int g = lane >> 4, cl = lane & 15;
    const int bid = blockIdx.x;
    const int b = (bid >> 1) & 3;
    const int t = 255 - (((bid >> 3) << 1) | (bid & 1));
    const int qw = t << 4;
    const int rowb = b << 12;

    short8 qh[2], ql[2];
    #pragma unroll
    for (int ks = 0; ks < 2; ++ks) {
        int off = ((rowb + qw + cl) << 6) + (ks << 5) + (g << 3);
        qh[ks] = *(const short8*)(qhi + off);
        ql[ks] = *(const short8*)(qlo + off);
    }

    f32x4 o[4];
    #pragma unroll
    for (int i = 0; i < 4; ++i) o[i] = (f32x4){0.f, 0.f, 0.f, 0.f};
    float m = -1e38f, lsp = 0.f;     // per-lane: running max for q=cl, partial sum (my g's kv only)

    const int nkv = (t >> 2) + 1;
    #pragma unroll 1
    for (int j = w; j < nkv; j += 4) {
        const int kv0 = j << 6;
        f32x4 sc[4];
        // QK^T, swapped operands; K loads hoisted per ct-pair (one wait per 8 loads)
        #pragma unroll
        for (int ch = 0; ch < 2; ++ch) {
            short8 ka[8];
            #pragma unroll
            for (int ci = 0; ci < 2; ++ci) {
                const int roff = ((rowb + kv0 + ((ch * 2 + ci) << 4) + cl) << 6) + (g << 3);
                ka[ci * 4 + 0] = *(const short8*)(khi + roff);
                ka[ci * 4 + 1] = *(const short8*)(khi + roff + 32);
                ka[ci * 4 + 2] = *(const short8*)(klo + roff);
                ka[ci * 4 + 3] = *(const short8*)(klo + roff + 32);
            }
            #pragma unroll
            for (int ci = 0; ci < 2; ++ci) {
                f32x4 s = (f32x4){0.f, 0.f, 0.f, 0.f};
                s = __builtin_amdgcn_mfma_f32_16x16x32_bf16(ka[ci * 4 + 0], qh[0], s, 0, 0, 0);
                s = __builtin_amdgcn_mfma_f32_16x16x32_bf16(ka[ci * 4 + 1], qh[1], s, 0, 0, 0);
                s = __builtin_amdgcn_mfma_f32_16x16x32_bf16(ka[ci * 4 + 0], ql[0], s, 0, 0, 0);
                s = __builtin_amdgcn_mfma_f32_16x16x32_bf16(ka[ci * 4 + 1], ql[1], s, 0, 0, 0);
                s = __builtin_amdgcn_mfma_f32_16x16x32_bf16(ka[ci * 4 + 2], qh[0], s, 0, 0, 0);
                s = __builtin_amdgcn_mfma_f32_16x16x32_bf16(ka[ci * 4 + 3], qh[1], s, 0, 0, 0);
                sc[ch * 2 + ci] = s;
            }
        }
        // causal mask: kv = kv0+(ct<<4)+(g<<2)+r, q = qw+cl
        if (j == nkv - 1) {
            #pragma unroll
            for (int ct = 0; ct < 4; ++ct)
                #pragma unroll
                for (int r = 0; r < 4; ++r)
                    if (kv0 + (ct << 4) + (g << 2) + r > qw + cl) sc[ct][r] = -1e30f;
        }
        // per-lane max tree over 16, then cross-g (2 shfls)
        float pm = fmaxf(fmaxf(fmaxf(sc[0][0], sc[0][1]), fmaxf(sc[0][2], sc[0][3])),
                         fmaxf(fmaxf(sc[1][0], sc[1][1]), fmaxf(sc[1][2], sc[1][3])));
        float pm2 = fmaxf(fmaxf(fmaxf(sc[2][0], sc[2][1]), fmaxf(sc[2][2], sc[2][3])),
                          fmaxf(fmaxf(sc[3][0], sc[3][1]), fmaxf(sc[3][2], sc[3][3])));
        pm = fmaxf(pm, pm2);
        pm = fmaxf(pm, __shfl_xor(pm, 16));
        pm = fmaxf(pm, __shfl_xor(pm, 32));
        const float mo = m;
        m = fmaxf(m, pm);
        const float rs = __expf(mo - m);
        // exp + pack P (row q=cl of Ps) + per-lane partial sum
        float psum = 0.f;
        #pragma unroll
        for (int ct = 0; ct < 4; ++ct) {
            float p0 = __expf(sc[ct][0] - m), p1 = __expf(sc[ct][1] - m);
            float p2 = __expf(sc[ct][2] - m), p3 = __expf(sc[ct][3] - m);
            psum += (p0 + p1) + (p2 + p3);
            short4v pk;
            pk[0] = f2bf(p0); pk[1] = f2bf(p1); pk[2] = f2bf(p2); pk[3] = f2bf(p3);
            *(short4v*)&Ps[w][cl][(ct << 4) + (g << 2)] = pk;
        }
        lsp = lsp * rs + psum;
        // o-rescale only when the running max moved; rs lives at lane q=cl,
        // o rows are q=(g<<2)+r -> broadcast via 4 parallel bpermutes
        if (__any(m > mo)) {
            float rs4[4];
            #pragma unroll
            for (int r = 0; r < 4; ++r) rs4[r] = __shfl(rs, (g << 2) + r);
            #pragma unroll
            for (int dt = 0; dt < 4; ++dt)
                #pragma unroll
                for (int r = 0; r < 4; ++r) o[dt][r] *= rs4[r];
        }
        // PV: identical to validated round-9 path (Ps[w][q][kv] contract unchanged)
        #pragma unroll
        for (int ks = 0; ks < 2; ++ks) {
            short8 pa = *(short8*)&Ps[w][cl][(ks << 5) + (g << 3)];
            #pragma unroll
            for (int dt = 0; dt < 4; ++dt) {
                short8 vf = *(const short8*)(vt + (((b << 6) + (dt << 4) + cl) << 12)
                                                + kv0 + (ks << 5) + (g << 3));
                o[dt] = __builtin_amdgcn_mfma_f32_16x16x32_bf16(pa, vf, o[dt], 0, 0, 0);
            }
        }
    }

    // finalize per-lane ls (sum partials across g), publish per-q state from g==0 lanes
    lsp += __shfl_xor(lsp, 16);
    lsp += __shfl_xor(lsp, 32);
    if (g == 0) { Cm[w][cl] = m; Cls[w][cl] = lsp; }
    #pragma unroll
    for (int dt = 0; dt < 4; ++dt)
        #pragma unroll
        for (int r = 0; r < 4; ++r)
            Co[w][(g << 2) + r][(dt << 4) + cl] = o[dt][r];
    __syncthreads();

    // exact flash-combine by wave 0 — UNCHANGED
    if (w == 0) {
        #pragma unroll
        for (int r = 0; r < 4; ++r) {
            const int row = (g << 2) + r;
            float M = fmaxf(fmaxf(Cm[0][row], Cm[1][row]), fmaxf(Cm[2][row], Cm[3][row]));
            float e0 = __expf(Cm[0][row] - M), e1 = __expf(Cm[1][row] - M);
            float e2 = __expf(Cm[2][row] - M), e3 = __expf(Cm[3][row] - M);
            float L = Cls[0][row] * e0 + Cls[1][row] * e1 + Cls[2][row] * e2 + Cls[3][row] * e3;
            float inv = 1.f / L;
            #pragma unroll
            for (int dt = 0; dt < 4; ++dt) {
                int d = (dt << 4) + cl;
                float O = Co[0][row][d] * e0 + Co[1][row][d] * e1
                        + Co[2][row][d] * e2 + Co[3][row][d] * e3;
                outp[(rowb + qw + row) * ND + d] = O * inv;
            }
        }
    }
}

extern "C" void kernel_launch(void* const* d_in, const int* in_sizes, int n_in,
                              void* d_out, int out_size, void* d_ws, size_t ws_size,
                              hipStream_t stream) {
    const float* x  = (const float*)d_in[0];
    // d_in[1] = mask (int32 tril) -- causal structure known, unused
    const float* WQ = (const float*)d_in[2];
    const float* WK = (const float*)d_in[3];
    const float* WV = (const float*)d_in[4];

    const size_t need = 786432u + 4u * 2097152u + 2097152u;   // 11,272,192 B
    if (ws_size < need) return;

    char* ws = (char*)d_ws;
    short* wthi = (short*)(ws);                                  // 384 KB
    short* wtlo = (short*)(ws + 393216);
    short* qhi  = (short*)(ws + 786432);                         // 2 MB each
    short* qlo  = (short*)(ws + 786432 + 1 * 2097152);
    short* khi  = (short*)(ws + 786432 + 2 * 2097152);
    short* klo  = (short*)(ws + 786432 + 3 * 2097152);
    short* vt   = (short*)(ws + 786432 + 4 * 2097152);           // V^T [B][64][4096]

    prep_wt<<<768, 256, 0, stream>>>(WQ, WK, WV, wthi, wtlo);
    proj_rope<<<2048, 64, 0, stream>>>(x, wthi, wtlo, qhi, qlo, khi, klo, vt);
    attn_fused<<<1024, 256, 0, stream>>>(qhi, qlo, khi, klo, vt, (float*)d_out);
}

// Round 11
// 143.227 us; speedup vs baseline: 2.1801x; 1.3485x over previous
//
#include <hip/hip_runtime.h>

typedef short short8  __attribute__((ext_vector_type(8)));
typedef short short4v __attribute__((ext_vector_type(4)));
typedef float f32x4   __attribute__((ext_vector_type(4)));
typedef int   i32x4   __attribute__((ext_vector_type(4)));

#define NB 4
#define NS 4096
#define NE 1024
#define ND 64

__device__ __forceinline__ short f2bf(float f) {
    unsigned u = __builtin_bit_cast(unsigned, f);
    u = (u + 0x7FFFu + ((u >> 16) & 1u)) >> 16;
    return (short)u;
}
__device__ __forceinline__ float bf2f(short s) {
    unsigned u = ((unsigned)(unsigned short)s) << 16;
    return __builtin_bit_cast(float, u);
}

// ---- kernel 1: W transpose + concat + bf16 hi/lo split (scale folded into W_Q) ----
__global__ void prep_wt(const float* __restrict__ WQ, const float* __restrict__ WK,
                        const float* __restrict__ WV,
                        short* __restrict__ wthi, short* __restrict__ wtlo) {
    int idx = blockIdx.x * 256 + threadIdx.x;     // 192*1024
    if (idx >= 192 * NE) return;
    int n = idx >> 10, k = idx & (NE - 1);
    int sel = n >> 6, d = n & 63;
    const float* W = (sel == 0) ? WQ : (sel == 1 ? WK : WV);
    float v = W[k * ND + d];
    if (sel == 0) v *= 0.125f;                    // 1/sqrt(64), exact power of 2
    short hi = f2bf(v);
    short lo = f2bf(v - bf2f(hi));
    wthi[idx] = hi;
    wtlo[idx] = lo;
}

// ---- kernel 2: QKV projection — UNCHANGED except V store goes to tile-blocked V^T:
//      vtb[b][s>>5][d][s&31]  (tile = contiguous 4KB, enables linear attn staging) ----
__global__ __launch_bounds__(64) void proj_rope(
        const float* __restrict__ x,
        const short* __restrict__ wthi, const short* __restrict__ wtlo,
        short* __restrict__ qhi, short* __restrict__ qlo,
        short* __restrict__ khi, short* __restrict__ klo,
        short* __restrict__ vtb) {
    const int lane = threadIdx.x;
    const int g = lane >> 4, cl = lane & 15;
    const int bid = blockIdx.x;
    const int rb = (bid >> 2) << 5;               // 32-row tile
    const int c0 = (bid & 3) * 48;                // 48-col tile

    f32x4 acc[2][3];
    #pragma unroll
    for (int i = 0; i < 2; ++i)
        #pragma unroll
        for (int j = 0; j < 3; ++j) acc[i][j] = (f32x4){0.f, 0.f, 0.f, 0.f};

    const float* xb  = x    + (size_t)(rb + cl) * NE + (g << 3);
    const short* bh0 = wthi + (size_t)(c0 + cl) * NE + (g << 3);
    const short* bl0 = wtlo + (size_t)(c0 + cl) * NE + (g << 3);

    #pragma unroll 2
    for (int k0 = 0; k0 < NE; k0 += 32) {
        short8 ah[2], al[2];
        #pragma unroll
        for (int rt = 0; rt < 2; ++rt) {
            const float* xp = xb + (rt << 4) * NE + k0;
            float4 v0 = *(const float4*)xp;
            float4 v1 = *(const float4*)(xp + 4);
            float vv[8] = {v0.x, v0.y, v0.z, v0.w, v1.x, v1.y, v1.z, v1.w};
            #pragma unroll
            for (int q = 0; q < 8; ++q) {
                short h = f2bf(vv[q]);
                ah[rt][q] = h;
                al[rt][q] = f2bf(vv[q] - bf2f(h));
            }
        }
        #pragma unroll
        for (int ct = 0; ct < 3; ++ct) {
            short8 bh = *(const short8*)(bh0 + (ct << 4) * NE + k0);
            short8 bl = *(const short8*)(bl0 + (ct << 4) * NE + k0);
            #pragma unroll
            for (int rt = 0; rt < 2; ++rt) {
                acc[rt][ct] = __builtin_amdgcn_mfma_f32_16x16x32_bf16(ah[rt], bh, acc[rt][ct], 0, 0, 0);
                acc[rt][ct] = __builtin_amdgcn_mfma_f32_16x16x32_bf16(ah[rt], bl, acc[rt][ct], 0, 0, 0);
                acc[rt][ct] = __builtin_amdgcn_mfma_f32_16x16x32_bf16(al[rt], bh, acc[rt][ct], 0, 0, 0);
            }
        }
    }

    #pragma unroll
    for (int rt = 0; rt < 2; ++rt) {
        #pragma unroll
        for (int ct = 0; ct < 3; ++ct) {
            int c = c0 + (ct << 4) + cl;
            #pragma unroll
            for (int r = 0; r < 4; ++r) {
                int row = rb + (rt << 4) + (g << 2) + r;
                int s = row & (NS - 1);
                int b = row >> 12;
                float val = acc[rt][ct][r];
                if (c < 128) {
                    int d = c & 63;
                    int p = d >> 1;
                    float freq = exp2f(-(float)p * 0.41524101186091903f);
                    float theta = (float)s * freq;
                    float sn = sinf(theta), cs = cosf(theta);
                    float partner = __shfl_xor(val, 1);
                    float rot = (c & 1) ? fmaf(partner, sn, val * cs)
                                        : fmaf(-partner, sn, val * cs);
                    short hi = f2bf(rot);
                    short lo = f2bf(rot - bf2f(hi));
                    int off = row * ND + d;
                    if (c < 64) { qhi[off] = hi; qlo[off] = lo; }
                    else        { khi[off] = hi; klo[off] = lo; }
                } else {
                    int d = c - 128;
                    vtb[(b << 18) + ((s >> 5) << 11) + (d << 5) + (s & 31)] = f2bf(val);
                }
            }
        }
    }
}

// ---- kernel 3: causal flash attention — per-wave LDS staging (coalesced, swizzled),
//      barrier-free KV-split, register prefetch. KVBLK=32. ----
__global__ __launch_bounds__(256) void attn_fused(
        const short* __restrict__ qhi, const short* __restrict__ qlo,
        const short* __restrict__ khi, const short* __restrict__ klo,
        const short* __restrict__ vtb, float* __restrict__ outp) {
    __shared__ char sm[54272];      // 4 x 12288 stage regions + 4 x 1280 Ps
    const int tid = threadIdx.x;
    const int lane = tid & 63, w = tid >> 6;
    const int g = lane >> 4, cl = lane & 15;
    const int bid = blockIdx.x;
    const int b = (bid >> 1) & 3;
    const int t = 255 - (((bid >> 3) << 1) | (bid & 1));   // heavy tiles first
    const int qw = t << 4;
    const int rowb = b << 12;

    char* SW  = sm + w * 12288;                 // Kh @0 (4KB), Kl @4096, Vt @8192
    short* Ps = (short*)(sm + 49152 + w * 1280);  // [16][40] shorts

    short8 qh[2], ql[2];
    #pragma unroll
    for (int ks = 0; ks < 2; ++ks) {
        int off = ((rowb + qw + cl) << 6) + (ks << 5) + (g << 3);
        qh[ks] = *(const short8*)(qhi + off);
        ql[ks] = *(const short8*)(qlo + off);
    }

    f32x4 o[4];
    #pragma unroll
    for (int i = 0; i < 4; ++i) o[i] = (f32x4){0.f, 0.f, 0.f, 0.f};
    float m = -1e38f, lsp = 0.f;

    const int nkv = (t >> 1) + 1;               // 32-wide kv tiles
    const short* kpB = khi + (rowb << 6);
    const short* lpB = klo + (rowb << 6);
    const short* vpB = vtb + (b << 18);

    i32x4 stK[4], stL[4], stV[4];
#define ISSUE(jj) {                                                          \
        const short* kp = kpB + ((jj) << 11);                                \
        const short* lp = lpB + ((jj) << 11);                                \
        const short* vp = vpB + ((jj) << 11);                                \
        _Pragma("unroll")                                                    \
        for (int i = 0; i < 4; ++i) {                                        \
            stK[i] = *(const i32x4*)(kp + (lane << 3) + (i << 9));           \
            stL[i] = *(const i32x4*)(lp + (lane << 3) + (i << 9));           \
            stV[i] = *(const i32x4*)(vp + (lane << 3) + (i << 9));           \
        } }

    if (w < nkv) {
        ISSUE(w);
        #pragma unroll 1
        for (int j = w; j < nkv; j += 4) {
            // stage regs -> LDS (swizzled); compiler inserts vmcnt wait on reg use
            #pragma unroll
            for (int i = 0; i < 4; ++i) {
                int c = lane + (i << 6);
                int kr = c >> 3, kc = c & 7;
                int koff = (kr << 7) + ((kc ^ (kr & 7)) << 4);
                *(i32x4*)(SW + koff) = stK[i];
                *(i32x4*)(SW + 4096 + koff) = stL[i];
                int vr = c >> 2, vc = c & 3;
                *(i32x4*)(SW + 8192 + (vr << 6) + ((vc ^ (vr & 3)) << 4)) = stV[i];
            }
            // prefetch next owned tile while computing this one
            int jn = j + 4;
            if (jn < nkv) ISSUE(jn);

            // QK^T (swapped operands): sc[ci][r] = S[kv=(ci<<4)+(g<<2)+r][q=cl]
            f32x4 sc[2];
            #pragma unroll
            for (int ci = 0; ci < 2; ++ci) {
                const int rbase = ((ci << 4) + cl) << 7;
                const int sw = (cl & 7) << 4;
                short8 kh0 = *(short8*)(SW + rbase + (((g << 4)     ) ^ sw));
                short8 kh1 = *(short8*)(SW + rbase + (((g << 4) + 64) ^ sw));
                short8 kl0 = *(short8*)(SW + 4096 + rbase + (((g << 4)     ) ^ sw));
                short8 kl1 = *(short8*)(SW + 4096 + rbase + (((g << 4) + 64) ^ sw));
                f32x4 s = (f32x4){0.f, 0.f, 0.f, 0.f};
                s = __builtin_amdgcn_mfma_f32_16x16x32_bf16(kh0, qh[0], s, 0, 0, 0);
                s = __builtin_amdgcn_mfma_f32_16x16x32_bf16(kh1, qh[1], s, 0, 0, 0);
                s = __builtin_amdgcn_mfma_f32_16x16x32_bf16(kh0, ql[0], s, 0, 0, 0);
                s = __builtin_amdgcn_mfma_f32_16x16x32_bf16(kh1, ql[1], s, 0, 0, 0);
                s = __builtin_amdgcn_mfma_f32_16x16x32_bf16(kl0, qh[0], s, 0, 0, 0);
                s = __builtin_amdgcn_mfma_f32_16x16x32_bf16(kl1, qh[1], s, 0, 0, 0);
                sc[ci] = s;
            }
            if (j == nkv - 1) {
                #pragma unroll
                for (int ci = 0; ci < 2; ++ci)
                    #pragma unroll
                    for (int r = 0; r < 4; ++r)
                        if ((j << 5) + (ci << 4) + (g << 2) + r > qw + cl) sc[ci][r] = -1e30f;
            }
            // lane-local softmax (row q=cl) + 2 cross-g shfls
            float pm = fmaxf(fmaxf(fmaxf(sc[0][0], sc[0][1]), fmaxf(sc[0][2], sc[0][3])),
                             fmaxf(fmaxf(sc[1][0], sc[1][1]), fmaxf(sc[1][2], sc[1][3])));
            pm = fmaxf(pm, __shfl_xor(pm, 16));
            pm = fmaxf(pm, __shfl_xor(pm, 32));
            const float mo = m;
            m = fmaxf(m, pm);
            const float rs = __expf(mo - m);
            float psum = 0.f;
            #pragma unroll
            for (int ci = 0; ci < 2; ++ci) {
                float p0 = __expf(sc[ci][0] - m), p1 = __expf(sc[ci][1] - m);
                float p2 = __expf(sc[ci][2] - m), p3 = __expf(sc[ci][3] - m);
                psum += (p0 + p1) + (p2 + p3);
                short4v pk;
                pk[0] = f2bf(p0); pk[1] = f2bf(p1); pk[2] = f2bf(p2); pk[3] = f2bf(p3);
                *(short4v*)(Ps + cl * 40 + (ci << 4) + (g << 2)) = pk;
            }
            lsp = lsp * rs + psum;
            if (__any(m > mo)) {
                float rs4[4];
                #pragma unroll
                for (int r = 0; r < 4; ++r) rs4[r] = __shfl(rs, (g << 2) + r);
                #pragma unroll
                for (int dt = 0; dt < 4; ++dt)
                    #pragma unroll
                    for (int r = 0; r < 4; ++r) o[dt][r] *= rs4[r];
            }
            // PV: A = P (rows q), B = V^T tile (rows d, k=kv 32)
            short8 pa = *(short8*)(Ps + cl * 40 + (g << 3));
            #pragma unroll
            for (int dt = 0; dt < 4; ++dt) {
                int vrow = (dt << 4) + cl;
                short8 vf = *(short8*)(SW + 8192 + (vrow << 6)
                                        + (((g << 4)) ^ ((vrow & 3) << 4)));
                o[dt] = __builtin_amdgcn_mfma_f32_16x16x32_bf16(pa, vf, o[dt], 0, 0, 0);
            }
        }
    }
#undef ISSUE

    // publish partials into own stage region (loop done -> safe alias)
    {
        float* Co = (float*)SW;                  // [16][66] floats
        #pragma unroll
        for (int dt = 0; dt < 4; ++dt)
            #pragma unroll
            for (int r = 0; r < 4; ++r)
                Co[((g << 2) + r) * 66 + (dt << 4) + cl] = o[dt][r];
        lsp += __shfl_xor(lsp, 16);
        lsp += __shfl_xor(lsp, 32);
        if (g == 0) {
            *(float*)(SW + 4224 + (cl << 2)) = m;
            *(float*)(SW + 4288 + (cl << 2)) = lsp;
        }
    }
    __syncthreads();

    // exact flash-combine by wave 0
    if (w == 0) {
        #pragma unroll
        for (int r = 0; r < 4; ++r) {
            const int row = (g << 2) + r;
            float mv[4], lv[4];
            #pragma unroll
            for (int v = 0; v < 4; ++v) {
                mv[v] = *(const float*)(sm + v * 12288 + 4224 + (row << 2));
                lv[v] = *(const float*)(sm + v * 12288 + 4288 + (row << 2));
            }
            float M = fmaxf(fmaxf(mv[0], mv[1]), fmaxf(mv[2], mv[3]));
            float e[4];
            float L = 0.f;
            #pragma unroll
            for (int v = 0; v < 4; ++v) { e[v] = __expf(mv[v] - M); L += lv[v] * e[v]; }
            float inv = 1.f / L;
            #pragma unroll
            for (int dt = 0; dt < 4; ++dt) {
                int d = (dt << 4) + cl;
                float O = 0.f;
                #pragma unroll
                for (int v = 0; v < 4; ++v)
                    O += ((const float*)(sm + v * 12288))[row * 66 + d] * e[v];
                outp[(rowb + qw + row) * ND + d] = O * inv;
            }
        }
    }
}

extern "C" void kernel_launch(void* const* d_in, const int* in_sizes, int n_in,
                              void* d_out, int out_size, void* d_ws, size_t ws_size,
                              hipStream_t stream) {
    const float* x  = (const float*)d_in[0];
    // d_in[1] = mask (int32 tril) -- causal structure known, unused
    const float* WQ = (const float*)d_in[2];
    const float* WK = (const float*)d_in[3];
    const float* WV = (const float*)d_in[4];

    const size_t need = 786432u + 4u * 2097152u + 2097152u;   // 11,272,192 B
    if (ws_size < need) return;

    char* ws = (char*)d_ws;
    short* wthi = (short*)(ws);                                  // 384 KB
    short* wtlo = (short*)(ws + 393216);
    short* qhi  = (short*)(ws + 786432);                         // 2 MB each
    short* qlo  = (short*)(ws + 786432 + 1 * 2097152);
    short* khi  = (short*)(ws + 786432 + 2 * 2097152);
    short* klo  = (short*)(ws + 786432 + 3 * 2097152);
    short* vtb  = (short*)(ws + 786432 + 4 * 2097152);           // V^T tile-blocked [B][128][64][32]

    prep_wt<<<768, 256, 0, stream>>>(WQ, WK, WV, wthi, wtlo);
    proj_rope<<<2048, 64, 0, stream>>>(x, wthi, wtlo, qhi, qlo, khi, klo, vtb);
    attn_fused<<<1024, 256, 0, stream>>>(qhi, qlo, khi, klo, vtb, (float*)d_out);
}